// Round 1
// baseline (800.534 us; speedup 1.0000x reference)
//
#include <hip/hip_runtime.h>
#include <hip/hip_bf16.h>
#include <math.h>

#define N_NODES 20000
#define N_EDG   320000
#define NB      64
#define EMBD    32
#define HIDD    128
#define NHEAD   4
#define OUTC    512      // H * HID
#define LN_EPS  1e-5f
#define NEG_SLOPE 0.2f

__device__ __forceinline__ float lrelu(float x){ return x >= 0.f ? x : NEG_SLOPE * x; }

// ---------------- CSR construction ----------------
__global__ void k_deg(const int* __restrict__ dst, int* __restrict__ deg){
  int e = blockIdx.x * blockDim.x + threadIdx.x;
  if (e < N_EDG) atomicAdd(&deg[dst[e]], 1);
}

__global__ __launch_bounds__(1024) void k_scan(const int* __restrict__ deg,
                                               int* __restrict__ rowptr,
                                               int* __restrict__ cursor){
  __shared__ int sums[1024];
  const int CH = (N_NODES + 1023) / 1024;   // 20
  int t = threadIdx.x;
  int start = t * CH;
  int end = min(start + CH, N_NODES);
  int s = 0;
  for (int i = start; i < end; ++i) s += deg[i];
  sums[t] = s;
  __syncthreads();
  for (int off = 1; off < 1024; off <<= 1){
    int v = (t >= off) ? sums[t - off] : 0;
    __syncthreads();
    sums[t] += v;
    __syncthreads();
  }
  int run = (t > 0) ? sums[t - 1] : 0;
  for (int i = start; i < end; ++i){
    rowptr[i] = run; cursor[i] = run; run += deg[i];
  }
  if (t == 0) rowptr[N_NODES] = sums[1023];
}

__global__ void k_scatter(const int* __restrict__ src, const int* __restrict__ dst,
                          int* __restrict__ cursor,
                          int* __restrict__ csr_src, int* __restrict__ csr_eid){
  int e = blockIdx.x * blockDim.x + threadIdx.x;
  if (e < N_EDG){
    int d = dst[e];
    int p = atomicAdd(&cursor[d], 1);
    csr_src[p] = src[e];
    csr_eid[p] = e;
  }
}

// loop_attr[n] = mean of incoming edge_attr (fill_value='mean'); 2 nodes per 64-thread block
__global__ __launch_bounds__(64) void k_loopattr(const float* __restrict__ ea,
                                                 const int* __restrict__ rowptr,
                                                 const int* __restrict__ csr_eid,
                                                 float* __restrict__ loop_attr){
  int n = blockIdx.x * 2 + (threadIdx.x >> 5);
  int k = threadIdx.x & 31;
  if (n >= N_NODES) return;
  int rs = rowptr[n], re = rowptr[n + 1];
  float s = 0.f;
  for (int p = rs; p < re; ++p){
    int e = csr_eid[p];
    s += ea[(size_t)e * EMBD + k];
  }
  float d = (float)(re - rs);
  loop_attr[(size_t)n * EMBD + k] = s / fmaxf(d, 1.f);
}

// ---------------- per-layer: attention-vector folding ----------------
// vfold layout (floats): [0,512) v_src[k*4+h], [512,1024) v_dst[k*4+h], [1024,1152) v_e[k*4+h]
__global__ void k_fold(const float* __restrict__ W, const float* __restrict__ We,
                       const float* __restrict__ a_src, const float* __restrict__ a_dst,
                       const float* __restrict__ a_e,
                       float* __restrict__ vfold, int in_dim){
  int j = blockIdx.x * blockDim.x + threadIdx.x;
  int nsrc = in_dim * NHEAD;
  if (j < nsrc){
    int k = j >> 2, h = j & 3;
    float s = 0.f;
    for (int c = 0; c < HIDD; ++c) s += W[k * OUTC + h * HIDD + c] * a_src[h * HIDD + c];
    vfold[k * 4 + h] = s;
  } else if (j < 2 * nsrc){
    int jj = j - nsrc; int k = jj >> 2, h = jj & 3;
    float s = 0.f;
    for (int c = 0; c < HIDD; ++c) s += W[k * OUTC + h * HIDD + c] * a_dst[h * HIDD + c];
    vfold[512 + k * 4 + h] = s;
  } else if (j < 2 * nsrc + EMBD * NHEAD){
    int jj = j - 2 * nsrc; int k = jj >> 2, h = jj & 3;
    float s = 0.f;
    for (int c = 0; c < HIDD; ++c) s += We[k * OUTC + h * HIDD + c] * a_e[h * HIDD + c];
    vfold[1024 + k * 4 + h] = s;
  }
}

// ---------------- h = X @ W  (M x K) * (K x 512), f32 tiled ----------------
#define BM 64
#define BN 64
#define BK 32
__global__ __launch_bounds__(256) void k_gemm(const float* __restrict__ X,
                                              const float* __restrict__ W,
                                              float* __restrict__ Hb,
                                              int M, int K){
  __shared__ float As[BK][BM + 1];
  __shared__ float Bs[BK][BN + 1];
  int bm = blockIdx.y * BM, bn = blockIdx.x * BN;
  int t = threadIdx.x;
  int tx = t & 15, ty = t >> 4;
  float acc[4][4];
  #pragma unroll
  for (int i = 0; i < 4; ++i)
    #pragma unroll
    for (int j = 0; j < 4; ++j) acc[i][j] = 0.f;

  for (int k0 = 0; k0 < K; k0 += BK){
    #pragma unroll
    for (int i = 0; i < 8; ++i){
      int idx = t + i * 256;          // 0..2047
      int kk = idx & 31, mm = idx >> 5;
      int gm = bm + mm;
      As[kk][mm] = (gm < M) ? X[(size_t)gm * K + k0 + kk] : 0.f;
    }
    #pragma unroll
    for (int i = 0; i < 8; ++i){
      int idx = t + i * 256;
      int nn = idx & 63, kk = idx >> 6;
      Bs[kk][nn] = W[(size_t)(k0 + kk) * OUTC + bn + nn];
    }
    __syncthreads();
    #pragma unroll
    for (int kk = 0; kk < BK; ++kk){
      float rA[4], rB[4];
      #pragma unroll
      for (int i = 0; i < 4; ++i) rA[i] = As[kk][ty * 4 + i];
      #pragma unroll
      for (int j = 0; j < 4; ++j) rB[j] = Bs[kk][tx * 4 + j];
      #pragma unroll
      for (int i = 0; i < 4; ++i)
        #pragma unroll
        for (int j = 0; j < 4; ++j) acc[i][j] = fmaf(rA[i], rB[j], acc[i][j]);
    }
    __syncthreads();
  }
  #pragma unroll
  for (int i = 0; i < 4; ++i){
    int gm = bm + ty * 4 + i;
    if (gm < M){
      #pragma unroll
      for (int j = 0; j < 4; ++j)
        Hb[(size_t)gm * OUTC + bn + tx * 4 + j] = acc[i][j];
    }
  }
}

// ---------------- per-node logits: s_src, s_dst, self-loop logit ----------------
__global__ __launch_bounds__(256) void k_nodelin(const float* __restrict__ X,
                                                 const float* __restrict__ vfold,
                                                 const float* __restrict__ loop_attr,
                                                 float* __restrict__ s_src, float* __restrict__ s_dst,
                                                 float* __restrict__ al_loop, int in_dim){
  __shared__ float vs[1152];
  for (int i = threadIdx.x; i < 1152; i += 256) vs[i] = vfold[i];
  __syncthreads();
  int n = blockIdx.x * blockDim.x + threadIdx.x;
  if (n >= N_NODES) return;
  float a0=0,a1=0,a2=0,a3=0, d0=0,d1=0,d2=0,d3=0;
  const float* xr = X + (size_t)n * in_dim;
  for (int k = 0; k < in_dim; ++k){
    float xv = xr[k];
    a0 += xv * vs[k*4+0]; a1 += xv * vs[k*4+1]; a2 += xv * vs[k*4+2]; a3 += xv * vs[k*4+3];
    d0 += xv * vs[512+k*4+0]; d1 += xv * vs[512+k*4+1]; d2 += xv * vs[512+k*4+2]; d3 += xv * vs[512+k*4+3];
  }
  float e0=0,e1=0,e2=0,e3=0;
  const float* lr = loop_attr + (size_t)n * EMBD;
  #pragma unroll
  for (int k = 0; k < EMBD; ++k){
    float lv = lr[k];
    e0 += lv * vs[1024+k*4+0]; e1 += lv * vs[1024+k*4+1]; e2 += lv * vs[1024+k*4+2]; e3 += lv * vs[1024+k*4+3];
  }
  ((float4*)s_src)[n] = make_float4(a0,a1,a2,a3);
  ((float4*)s_dst)[n] = make_float4(d0,d1,d2,d3);
  float4 ll;
  ll.x = lrelu(a0+d0+e0); ll.y = lrelu(a1+d1+e1);
  ll.z = lrelu(a2+d2+e2); ll.w = lrelu(a3+d3+e3);
  ((float4*)al_loop)[n] = ll;
}

// ---------------- per-edge partial logit (no s_dst, no leaky yet) ----------------
__global__ __launch_bounds__(256) void k_edgepart(const float* __restrict__ ea,
                                                  const int* __restrict__ src,
                                                  const float* __restrict__ vfold,
                                                  const float* __restrict__ s_src,
                                                  float* __restrict__ alp){
  __shared__ float ve[128];
  if (threadIdx.x < 128) ve[threadIdx.x] = vfold[1024 + threadIdx.x];
  __syncthreads();
  int e = blockIdx.x * blockDim.x + threadIdx.x;
  if (e >= N_EDG) return;
  float e0=0,e1=0,e2=0,e3=0;
  const float* er = ea + (size_t)e * EMBD;
  #pragma unroll
  for (int k = 0; k < EMBD; ++k){
    float v = er[k];
    e0 += v * ve[k*4+0]; e1 += v * ve[k*4+1]; e2 += v * ve[k*4+2]; e3 += v * ve[k*4+3];
  }
  int s = src[e];
  float4 ss = ((const float4*)s_src)[s];
  ((float4*)alp)[e] = make_float4(ss.x+e0, ss.y+e1, ss.z+e2, ss.w+e3);
}

// ---------------- per-node aggregation + head mean + bias + LN + ReLU ----------------
__global__ __launch_bounds__(256) void k_aggr(const float* __restrict__ Hb,
                                              const float* __restrict__ alp,
                                              const float* __restrict__ s_dst,
                                              const float* __restrict__ al_loop,
                                              const int* __restrict__ rowptr,
                                              const int* __restrict__ csr_src,
                                              const int* __restrict__ csr_eid,
                                              const float* __restrict__ bias,
                                              const float* __restrict__ lng,
                                              const float* __restrict__ lnb,
                                              float* __restrict__ Xout){
  int n = blockIdx.x;
  int tid = threadIdx.x;
  int rs = rowptr[n], re = rowptr[n + 1];
  float4 sd = ((const float4*)s_dst)[n];
  float4 ll = ((const float4*)al_loop)[n];   // self-loop logit (leaky applied)

  // ---- pass 1: max ----
  float m0 = ll.x, m1 = ll.y, m2 = ll.z, m3 = ll.w;
  for (int p = rs + tid; p < re; p += 256){
    int e = csr_eid[p];
    float4 ap = ((const float4*)alp)[e];
    m0 = fmaxf(m0, lrelu(ap.x + sd.x));
    m1 = fmaxf(m1, lrelu(ap.y + sd.y));
    m2 = fmaxf(m2, lrelu(ap.z + sd.z));
    m3 = fmaxf(m3, lrelu(ap.w + sd.w));
  }
  #pragma unroll
  for (int off = 32; off > 0; off >>= 1){
    m0 = fmaxf(m0, __shfl_xor(m0, off));
    m1 = fmaxf(m1, __shfl_xor(m1, off));
    m2 = fmaxf(m2, __shfl_xor(m2, off));
    m3 = fmaxf(m3, __shfl_xor(m3, off));
  }
  __shared__ float wred[4][4];
  int wv = tid >> 6;
  if ((tid & 63) == 0){ wred[wv][0]=m0; wred[wv][1]=m1; wred[wv][2]=m2; wred[wv][3]=m3; }
  __syncthreads();
  m0 = fmaxf(fmaxf(wred[0][0], wred[1][0]), fmaxf(wred[2][0], wred[3][0]));
  m1 = fmaxf(fmaxf(wred[0][1], wred[1][1]), fmaxf(wred[2][1], wred[3][1]));
  m2 = fmaxf(fmaxf(wred[0][2], wred[1][2]), fmaxf(wred[2][2], wred[3][2]));
  m3 = fmaxf(fmaxf(wred[0][3], wred[1][3]), fmaxf(wred[2][3], wred[3][3]));
  __syncthreads();

  // ---- pass 2: sum of exp ----
  float s0 = (tid == 0) ? expf(ll.x - m0) : 0.f;
  float s1 = (tid == 0) ? expf(ll.y - m1) : 0.f;
  float s2 = (tid == 0) ? expf(ll.z - m2) : 0.f;
  float s3 = (tid == 0) ? expf(ll.w - m3) : 0.f;
  for (int p = rs + tid; p < re; p += 256){
    int e = csr_eid[p];
    float4 ap = ((const float4*)alp)[e];
    s0 += expf(lrelu(ap.x + sd.x) - m0);
    s1 += expf(lrelu(ap.y + sd.y) - m1);
    s2 += expf(lrelu(ap.z + sd.z) - m2);
    s3 += expf(lrelu(ap.w + sd.w) - m3);
  }
  #pragma unroll
  for (int off = 32; off > 0; off >>= 1){
    s0 += __shfl_xor(s0, off);
    s1 += __shfl_xor(s1, off);
    s2 += __shfl_xor(s2, off);
    s3 += __shfl_xor(s3, off);
  }
  if ((tid & 63) == 0){ wred[wv][0]=s0; wred[wv][1]=s1; wred[wv][2]=s2; wred[wv][3]=s3; }
  __syncthreads();
  s0 = wred[0][0] + wred[1][0] + wred[2][0] + wred[3][0];
  s1 = wred[0][1] + wred[1][1] + wred[2][1] + wred[3][1];
  s2 = wred[0][2] + wred[1][2] + wred[2][2] + wred[3][2];
  s3 = wred[0][3] + wred[1][3] + wred[2][3] + wred[3][3];
  float inv0 = 1.f/s0, inv1 = 1.f/s1, inv2 = 1.f/s2, inv3 = 1.f/s3;

  // ---- pass 3: weighted accumulate of h[src] ----
  __shared__ int   sidx[256];
  __shared__ float wbuf[1024];
  int c0 = tid, c1 = tid + 256;
  int h0 = tid >> 7;          // 0 or 1 (uniform per wave)
  int h1 = h0 + 2;            // 2 or 3
  float eW0 = expf(ll.x - m0) * inv0;
  float eW1 = expf(ll.y - m1) * inv1;
  float eW2 = expf(ll.z - m2) * inv2;
  float eW3 = expf(ll.w - m3) * inv3;
  float wlc0 = h0 ? eW1 : eW0;
  float wlc1 = (h1 == 3) ? eW3 : eW2;
  float acc0 = wlc0 * Hb[(size_t)n * OUTC + c0];
  float acc1 = wlc1 * Hb[(size_t)n * OUTC + c1];

  for (int base = rs; base < re; base += 256){
    int cnt = min(256, re - base);
    __syncthreads();
    if (tid < cnt){
      int p = base + tid;
      int e = csr_eid[p];
      sidx[tid] = csr_src[p];
      float4 ap = ((const float4*)alp)[e];
      wbuf[tid*4+0] = expf(lrelu(ap.x + sd.x) - m0) * inv0;
      wbuf[tid*4+1] = expf(lrelu(ap.y + sd.y) - m1) * inv1;
      wbuf[tid*4+2] = expf(lrelu(ap.z + sd.z) - m2) * inv2;
      wbuf[tid*4+3] = expf(lrelu(ap.w + sd.w) - m3) * inv3;
    }
    __syncthreads();
    for (int j = 0; j < cnt; ++j){
      const float* hrow = Hb + (size_t)sidx[j] * OUTC;
      acc0 = fmaf(wbuf[j*4+h0], hrow[c0], acc0);
      acc1 = fmaf(wbuf[j*4+h1], hrow[c1], acc1);
    }
  }

  // ---- pass 4: head mean + bias + LayerNorm + ReLU ----
  __shared__ float A[512];
  A[c0] = acc0; A[c1] = acc1;
  __syncthreads();
  __shared__ float xv[128];
  __shared__ float rr[128];
  if (tid < 128){
    float xm = 0.25f * (A[tid] + A[tid+128] + A[tid+256] + A[tid+384]) + bias[tid];
    xv[tid] = xm;
    rr[tid] = xm;
  }
  __syncthreads();
  for (int off = 64; off > 0; off >>= 1){
    if (tid < off) rr[tid] += rr[tid + off];
    __syncthreads();
  }
  float mu = rr[0] * (1.f / 128.f);
  __syncthreads();
  if (tid < 128){ float dd = xv[tid] - mu; rr[tid] = dd * dd; }
  __syncthreads();
  for (int off = 64; off > 0; off >>= 1){
    if (tid < off) rr[tid] += rr[tid + off];
    __syncthreads();
  }
  float var = rr[0] * (1.f / 128.f);
  if (tid < 128){
    float y = (xv[tid] - mu) * rsqrtf(var + LN_EPS) * lng[tid] + lnb[tid];
    Xout[(size_t)n * HIDD + tid] = fmaxf(y, 0.f);
  }
}

// ---------------- global mean pool ----------------
__global__ void k_cnt(const int* __restrict__ batch, int* __restrict__ cnt){
  int n = blockIdx.x * blockDim.x + threadIdx.x;
  if (n < N_NODES) atomicAdd(&cnt[batch[n]], 1);
}
__global__ void k_poolsum(const float* __restrict__ X, const int* __restrict__ batch,
                          float* __restrict__ pool){
  int i = blockIdx.x * blockDim.x + threadIdx.x;
  if (i < N_NODES * HIDD){
    int n = i >> 7, c = i & 127;
    atomicAdd(&pool[batch[n] * HIDD + c], X[i]);
  }
}
__global__ void k_poolout(const float* __restrict__ pool, const int* __restrict__ cnt,
                          float* __restrict__ out){
  int i = blockIdx.x * blockDim.x + threadIdx.x;
  if (i < NB * HIDD){
    float c = (float)cnt[i >> 7];
    out[i] = pool[i] / fmaxf(c, 1.f);
  }
}

extern "C" void kernel_launch(void* const* d_in, const int* in_sizes, int n_in,
                              void* d_out, int out_size, void* d_ws, size_t ws_size,
                              hipStream_t stream){
  const float* x        = (const float*)d_in[0];
  const float* ea       = (const float*)d_in[1];
  const float* lin_w[3] = {(const float*)d_in[2], (const float*)d_in[3], (const float*)d_in[4]};
  const float* lin_edge = (const float*)d_in[5];
  const float* att_src  = (const float*)d_in[6];
  const float* att_dst  = (const float*)d_in[7];
  const float* att_edge = (const float*)d_in[8];
  const float* bias     = (const float*)d_in[9];
  const float* lng      = (const float*)d_in[10];
  const float* lnb      = (const float*)d_in[11];
  const int*   eidx     = (const int*)d_in[12];
  const int*   batch    = (const int*)d_in[13];
  const int*   srcp = eidx;
  const int*   dstp = eidx + N_EDG;

  char* ws = (char*)d_ws;
  size_t off = 0;
  auto alloc = [&](size_t bytes)->char*{
    size_t o = off;
    off = (off + bytes + 511) & ~(size_t)511;
    return ws + o;
  };
  int*   deg      = (int*)  alloc((size_t)N_NODES * 4);
  int*   rowptr   = (int*)  alloc((size_t)(N_NODES + 1) * 4);
  int*   cursor   = (int*)  alloc((size_t)N_NODES * 4);
  int*   csr_src  = (int*)  alloc((size_t)N_EDG * 4);
  int*   csr_eid  = (int*)  alloc((size_t)N_EDG * 4);
  float* lattr    = (float*)alloc((size_t)N_NODES * EMBD * 4);
  float* s_src    = (float*)alloc((size_t)N_NODES * 4 * 4);
  float* s_dst    = (float*)alloc((size_t)N_NODES * 4 * 4);
  float* al_loop  = (float*)alloc((size_t)N_NODES * 4 * 4);
  float* alp      = (float*)alloc((size_t)N_EDG * 4 * 4);
  float* vfold    = (float*)alloc((size_t)1152 * 4);
  float* hbuf     = (float*)alloc((size_t)N_NODES * OUTC * 4);
  float* xA       = (float*)alloc((size_t)N_NODES * HIDD * 4);
  float* xB       = (float*)alloc((size_t)N_NODES * HIDD * 4);
  float* pool     = (float*)alloc((size_t)NB * HIDD * 4);
  int*   cnt      = (int*)  alloc((size_t)NB * 4);

  hipMemsetAsync(deg, 0, (size_t)N_NODES * 4, stream);
  k_deg<<<(N_EDG + 255) / 256, 256, 0, stream>>>(dstp, deg);
  k_scan<<<1, 1024, 0, stream>>>(deg, rowptr, cursor);
  k_scatter<<<(N_EDG + 255) / 256, 256, 0, stream>>>(srcp, dstp, cursor, csr_src, csr_eid);
  k_loopattr<<<(N_NODES + 1) / 2, 64, 0, stream>>>(ea, rowptr, csr_eid, lattr);

  const float* xcur = x;
  float* xout = xA;
  for (int L = 0; L < 3; ++L){
    int in_dim = L ? HIDD : EMBD;
    const float* W  = lin_w[L];
    const float* We = lin_edge + (size_t)L * EMBD * OUTC;
    int fold_jobs = in_dim * 8 + 128;
    k_fold<<<(fold_jobs + 255) / 256, 256, 0, stream>>>(W, We,
        att_src + L * 512, att_dst + L * 512, att_edge + L * 512, vfold, in_dim);
    dim3 gg(OUTC / BN, (N_NODES + BM - 1) / BM);
    k_gemm<<<gg, 256, 0, stream>>>(xcur, W, hbuf, N_NODES, in_dim);
    k_nodelin<<<(N_NODES + 255) / 256, 256, 0, stream>>>(xcur, vfold, lattr,
        s_src, s_dst, al_loop, in_dim);
    k_edgepart<<<(N_EDG + 255) / 256, 256, 0, stream>>>(ea, srcp, vfold, s_src, alp);
    k_aggr<<<N_NODES, 256, 0, stream>>>(hbuf, alp, s_dst, al_loop, rowptr, csr_src, csr_eid,
        bias + L * HIDD, lng + L * HIDD, lnb + L * HIDD, xout);
    xcur = xout;
    xout = (L == 0) ? xB : xA;
  }

  hipMemsetAsync(pool, 0, (size_t)NB * HIDD * 4, stream);
  hipMemsetAsync(cnt, 0, (size_t)NB * 4, stream);
  k_cnt<<<(N_NODES + 255) / 256, 256, 0, stream>>>(batch, cnt);
  k_poolsum<<<((N_NODES * HIDD) + 255) / 256, 256, 0, stream>>>(xcur, batch, pool);
  k_poolout<<<((NB * HIDD) + 255) / 256, 256, 0, stream>>>(pool, cnt, (float*)d_out);
}

// Round 2
// 595.426 us; speedup vs baseline: 1.3445x; 1.3445x over previous
//
#include <hip/hip_runtime.h>
#include <hip/hip_bf16.h>
#include <math.h>

#define N_NODES 20000
#define N_EDG   320000
#define NB      64
#define EMBD    32
#define HIDD    128
#define NHEAD   4
#define OUTC    512      // H * HID
#define LN_EPS  1e-5f
#define NEG_SLOPE 0.2f

__device__ __forceinline__ float lrelu(float x){ return x >= 0.f ? x : NEG_SLOPE * x; }

// ---------------- CSR construction ----------------
__global__ void k_deg(const int* __restrict__ dst, int* __restrict__ deg){
  int e = blockIdx.x * blockDim.x + threadIdx.x;
  if (e < N_EDG) atomicAdd(&deg[dst[e]], 1);
}

__global__ __launch_bounds__(1024) void k_scan(const int* __restrict__ deg,
                                               int* __restrict__ rowptr,
                                               int* __restrict__ cursor){
  __shared__ int sums[1024];
  const int CH = (N_NODES + 1023) / 1024;   // 20
  int t = threadIdx.x;
  int start = t * CH;
  int end = min(start + CH, N_NODES);
  int s = 0;
  for (int i = start; i < end; ++i) s += deg[i];
  sums[t] = s;
  __syncthreads();
  for (int off = 1; off < 1024; off <<= 1){
    int v = (t >= off) ? sums[t - off] : 0;
    __syncthreads();
    sums[t] += v;
    __syncthreads();
  }
  int run = (t > 0) ? sums[t - 1] : 0;
  for (int i = start; i < end; ++i){
    rowptr[i] = run; cursor[i] = run; run += deg[i];
  }
  if (t == 0) rowptr[N_NODES] = sums[1023];
}

__global__ void k_scatter(const int* __restrict__ src, const int* __restrict__ dst,
                          int* __restrict__ cursor,
                          int* __restrict__ csr_src, int* __restrict__ csr_eid,
                          int* __restrict__ epos){
  int e = blockIdx.x * blockDim.x + threadIdx.x;
  if (e < N_EDG){
    int d = dst[e];
    int p = atomicAdd(&cursor[d], 1);
    csr_src[p] = src[e];
    csr_eid[p] = e;
    epos[e] = p;
  }
}

// loop_attr[n] = mean of incoming edge_attr (fill_value='mean')
__global__ __launch_bounds__(64) void k_loopattr(const float* __restrict__ ea,
                                                 const int* __restrict__ rowptr,
                                                 const int* __restrict__ csr_eid,
                                                 float* __restrict__ loop_attr){
  int n = blockIdx.x * 2 + (threadIdx.x >> 5);
  int k = threadIdx.x & 31;
  if (n >= N_NODES) return;
  int rs = rowptr[n], re = rowptr[n + 1];
  float s = 0.f;
  for (int p = rs; p < re; ++p){
    int e = csr_eid[p];
    s += ea[(size_t)e * EMBD + k];
  }
  float d = (float)(re - rs);
  loop_attr[(size_t)n * EMBD + k] = s / fmaxf(d, 1.f);
}

// graph boundaries from sorted batch: bnd[g] = first n with batch[n] >= g
__global__ void k_bounds(const int* __restrict__ batch, int* __restrict__ bnd){
  int n = blockIdx.x * blockDim.x + threadIdx.x;
  if (n >= N_NODES) return;
  int b = batch[n];
  int bp = (n == 0) ? -1 : batch[n - 1];
  for (int g = bp + 1; g <= b; ++g) bnd[g] = n;
  if (n == N_NODES - 1){
    for (int g = b + 1; g <= NB; ++g) bnd[g] = N_NODES;
  }
}

// ---------------- attention-vector folding (all 3 layers, one launch) ----------------
// vfold[L] layout: [0,512) v_src[k*4+h], [512,1024) v_dst, [1024,1152) v_e
__global__ void k_fold(const float* __restrict__ W0, const float* __restrict__ W1,
                       const float* __restrict__ W2, const float* __restrict__ lin_edge,
                       const float* __restrict__ att_src, const float* __restrict__ att_dst,
                       const float* __restrict__ att_edge, float* __restrict__ vfold){
  int L = blockIdx.y;
  int in_dim = L ? HIDD : EMBD;
  const float* W  = (L == 0) ? W0 : ((L == 1) ? W1 : W2);
  const float* We = lin_edge + (size_t)L * EMBD * OUTC;
  const float* as = att_src + L * 512;
  const float* ad = att_dst + L * 512;
  const float* ae = att_edge + L * 512;
  float* vf = vfold + L * 1152;
  int j = blockIdx.x * blockDim.x + threadIdx.x;
  int nsrc = in_dim * NHEAD;
  if (j < nsrc){
    int k = j >> 2, h = j & 3;
    float s = 0.f;
    for (int c = 0; c < HIDD; ++c) s += W[k * OUTC + h * HIDD + c] * as[h * HIDD + c];
    vf[k * 4 + h] = s;
  } else if (j < 2 * nsrc){
    int jj = j - nsrc; int k = jj >> 2, h = jj & 3;
    float s = 0.f;
    for (int c = 0; c < HIDD; ++c) s += W[k * OUTC + h * HIDD + c] * ad[h * HIDD + c];
    vf[512 + k * 4 + h] = s;
  } else if (j < 2 * nsrc + EMBD * NHEAD){
    int jj = j - 2 * nsrc; int k = jj >> 2, h = jj & 3;
    float s = 0.f;
    for (int c = 0; c < HIDD; ++c) s += We[k * OUTC + h * HIDD + c] * ae[h * HIDD + c];
    vf[1024 + k * 4 + h] = s;
  }
}

// ---------------- h = X @ W : [M,K]x[K,512], 64x128 tile, 4x8 micro ----------------
#define GBM 64
#define GBN 128
#define GBK 32
__global__ __launch_bounds__(256) void k_gemm(const float* __restrict__ X,
                                              const float* __restrict__ W,
                                              float* __restrict__ Hb,
                                              int M, int K){
  __shared__ float As[GBK][GBM + 4];
  __shared__ float Bs[GBK][GBN + 4];
  int bm = blockIdx.y * GBM, bn = blockIdx.x * GBN;
  int t = threadIdx.x;
  int tx = t & 15, ty = t >> 4;
  float acc[4][8];
  #pragma unroll
  for (int i = 0; i < 4; ++i)
    #pragma unroll
    for (int j = 0; j < 8; ++j) acc[i][j] = 0.f;

  for (int k0 = 0; k0 < K; k0 += GBK){
    // A tile: 64 rows x 32 k. 512 float4s; thread does 2.
    #pragma unroll
    for (int i = 0; i < 2; ++i){
      int f = t + i * 256;
      int row = f >> 3, kc = f & 7;
      int gm = bm + row;
      float4 xv = make_float4(0.f, 0.f, 0.f, 0.f);
      if (gm < M) xv = *(const float4*)(X + (size_t)gm * K + k0 + kc * 4);
      As[kc * 4 + 0][row] = xv.x;
      As[kc * 4 + 1][row] = xv.y;
      As[kc * 4 + 2][row] = xv.z;
      As[kc * 4 + 3][row] = xv.w;
    }
    // B tile: 32 k x 128 n. 1024 float4s; thread does 4.
    #pragma unroll
    for (int i = 0; i < 4; ++i){
      int f = t + i * 256;
      int kk = f >> 5, nc = f & 31;
      *(float4*)&Bs[kk][nc * 4] = *(const float4*)(W + (size_t)(k0 + kk) * OUTC + bn + nc * 4);
    }
    __syncthreads();
    #pragma unroll
    for (int kk = 0; kk < GBK; ++kk){
      float4 rA  = *(const float4*)&As[kk][ty * 4];
      float4 rB0 = *(const float4*)&Bs[kk][tx * 4];
      float4 rB1 = *(const float4*)&Bs[kk][64 + tx * 4];
      float a[4] = {rA.x, rA.y, rA.z, rA.w};
      float b[8] = {rB0.x, rB0.y, rB0.z, rB0.w, rB1.x, rB1.y, rB1.z, rB1.w};
      #pragma unroll
      for (int i = 0; i < 4; ++i)
        #pragma unroll
        for (int j = 0; j < 8; ++j) acc[i][j] = fmaf(a[i], b[j], acc[i][j]);
    }
    __syncthreads();
  }
  #pragma unroll
  for (int i = 0; i < 4; ++i){
    int gm = bm + ty * 4 + i;
    if (gm < M){
      float* cr = Hb + (size_t)gm * OUTC + bn;
      *(float4*)(cr + tx * 4)      = make_float4(acc[i][0], acc[i][1], acc[i][2], acc[i][3]);
      *(float4*)(cr + 64 + tx * 4) = make_float4(acc[i][4], acc[i][5], acc[i][6], acc[i][7]);
    }
  }
}

// ---------------- per-node logits: s_src, s_dst, self-loop logit ----------------
__global__ __launch_bounds__(256) void k_nodelin(const float* __restrict__ X,
                                                 const float* __restrict__ vfold,
                                                 const float* __restrict__ loop_attr,
                                                 float* __restrict__ s_src, float* __restrict__ s_dst,
                                                 float* __restrict__ al_loop, int in_dim){
  __shared__ float vs[1152];
  for (int i = threadIdx.x; i < 1152; i += 256) vs[i] = vfold[i];
  __syncthreads();
  int n = blockIdx.x * blockDim.x + threadIdx.x;
  if (n >= N_NODES) return;
  float a[4] = {0,0,0,0}, d[4] = {0,0,0,0};
  const float* xr = X + (size_t)n * in_dim;
  for (int k4 = 0; k4 < in_dim; k4 += 4){
    float4 xv = *(const float4*)(xr + k4);
    #pragma unroll
    for (int h = 0; h < 4; ++h){
      a[h] += xv.x * vs[(k4+0)*4+h] + xv.y * vs[(k4+1)*4+h]
            + xv.z * vs[(k4+2)*4+h] + xv.w * vs[(k4+3)*4+h];
      d[h] += xv.x * vs[512+(k4+0)*4+h] + xv.y * vs[512+(k4+1)*4+h]
            + xv.z * vs[512+(k4+2)*4+h] + xv.w * vs[512+(k4+3)*4+h];
    }
  }
  float ev[4] = {0,0,0,0};
  const float* lr = loop_attr + (size_t)n * EMBD;
  #pragma unroll
  for (int k4 = 0; k4 < EMBD; k4 += 4){
    float4 lv = *(const float4*)(lr + k4);
    #pragma unroll
    for (int h = 0; h < 4; ++h){
      ev[h] += lv.x * vs[1024+(k4+0)*4+h] + lv.y * vs[1024+(k4+1)*4+h]
             + lv.z * vs[1024+(k4+2)*4+h] + lv.w * vs[1024+(k4+3)*4+h];
    }
  }
  ((float4*)s_src)[n] = make_float4(a[0], a[1], a[2], a[3]);
  ((float4*)s_dst)[n] = make_float4(d[0], d[1], d[2], d[3]);
  float4 ll;
  ll.x = lrelu(a[0]+d[0]+ev[0]); ll.y = lrelu(a[1]+d[1]+ev[1]);
  ll.z = lrelu(a[2]+d[2]+ev[2]); ll.w = lrelu(a[3]+d[3]+ev[3]);
  ((float4*)al_loop)[n] = ll;
}

// ---------------- per-edge FULL logit (leaky applied), written in CSR order ----------------
__global__ __launch_bounds__(256) void k_edgepart(const float* __restrict__ ea,
                                                  const int* __restrict__ src,
                                                  const int* __restrict__ dst,
                                                  const int* __restrict__ epos,
                                                  const float* __restrict__ vfold,
                                                  const float* __restrict__ s_src,
                                                  const float* __restrict__ s_dst,
                                                  float* __restrict__ alpc){
  __shared__ float ve[128];
  if (threadIdx.x < 128) ve[threadIdx.x] = vfold[1024 + threadIdx.x];
  __syncthreads();
  int e = blockIdx.x * blockDim.x + threadIdx.x;
  if (e >= N_EDG) return;
  float ev[4] = {0,0,0,0};
  const float* er = ea + (size_t)e * EMBD;
  #pragma unroll
  for (int k4 = 0; k4 < EMBD; k4 += 4){
    float4 v = *(const float4*)(er + k4);
    #pragma unroll
    for (int h = 0; h < 4; ++h){
      ev[h] += v.x * ve[(k4+0)*4+h] + v.y * ve[(k4+1)*4+h]
             + v.z * ve[(k4+2)*4+h] + v.w * ve[(k4+3)*4+h];
    }
  }
  float4 ss = ((const float4*)s_src)[src[e]];
  float4 dd = ((const float4*)s_dst)[dst[e]];
  float4 o;
  o.x = lrelu(ss.x + dd.x + ev[0]);
  o.y = lrelu(ss.y + dd.y + ev[1]);
  o.z = lrelu(ss.z + dd.z + ev[2]);
  o.w = lrelu(ss.w + dd.w + ev[3]);
  ((float4*)alpc)[epos[e]] = o;
}

// ---------------- wave-per-node aggregation + head mean + bias + LN + ReLU ----------------
__device__ __forceinline__ float wmax(float v){
  #pragma unroll
  for (int off = 32; off > 0; off >>= 1) v = fmaxf(v, __shfl_xor(v, off));
  return v;
}
__device__ __forceinline__ float wsum(float v){
  #pragma unroll
  for (int off = 32; off > 0; off >>= 1) v += __shfl_xor(v, off);
  return v;
}

__global__ __launch_bounds__(256) void k_aggr(const float* __restrict__ Hb,
                                              const float* __restrict__ alpc,
                                              const float* __restrict__ al_loop,
                                              const int* __restrict__ rowptr,
                                              const int* __restrict__ csr_src,
                                              const float* __restrict__ bias,
                                              const float* __restrict__ lng,
                                              const float* __restrict__ lnb,
                                              float* __restrict__ Xout){
  int wid  = threadIdx.x >> 6;
  int lane = threadIdx.x & 63;
  int n = blockIdx.x * 4 + wid;
  if (n >= N_NODES) return;
  int rs = rowptr[n], re = rowptr[n + 1];

  float4 ll = ((const float4*)al_loop)[n];
  float m0 = ll.x, m1 = ll.y, m2 = ll.z, m3 = ll.w;
  float s0 = 1.f, s1 = 1.f, s2 = 1.f, s3 = 1.f;   // self-loop: exp(ll-ll)=1

  // acc[h] covers channels (2*lane, 2*lane+1) of head h; init with self-loop (weight 1 pre-scale)
  const float2* hn2 = (const float2*)(Hb + (size_t)n * OUTC);
  float2 acc[4];
  #pragma unroll
  for (int h = 0; h < 4; ++h) acc[h] = hn2[h * 64 + lane];

  for (int base = rs; base < re; base += 64){
    int cnt = min(64, re - base);
    int j = base + lane;
    float4 v = make_float4(-1e30f, -1e30f, -1e30f, -1e30f);
    int sv = 0;
    if (lane < cnt){
      v = ((const float4*)alpc)[j];
      sv = csr_src[j];
    }
    float nm0 = fmaxf(m0, wmax(v.x));
    float nm1 = fmaxf(m1, wmax(v.y));
    float nm2 = fmaxf(m2, wmax(v.z));
    float nm3 = fmaxf(m3, wmax(v.w));
    float e0 = (lane < cnt) ? __expf(v.x - nm0) : 0.f;
    float e1 = (lane < cnt) ? __expf(v.y - nm1) : 0.f;
    float e2 = (lane < cnt) ? __expf(v.z - nm2) : 0.f;
    float e3 = (lane < cnt) ? __expf(v.w - nm3) : 0.f;
    float r0 = __expf(m0 - nm0), r1 = __expf(m1 - nm1);
    float r2 = __expf(m2 - nm2), r3 = __expf(m3 - nm3);
    s0 = s0 * r0 + wsum(e0);
    s1 = s1 * r1 + wsum(e1);
    s2 = s2 * r2 + wsum(e2);
    s3 = s3 * r3 + wsum(e3);
    acc[0].x *= r0; acc[0].y *= r0;
    acc[1].x *= r1; acc[1].y *= r1;
    acc[2].x *= r2; acc[2].y *= r2;
    acc[3].x *= r3; acc[3].y *= r3;
    m0 = nm0; m1 = nm1; m2 = nm2; m3 = nm3;

    #pragma unroll 4
    for (int jj = 0; jj < cnt; ++jj){
      float w0 = __shfl(e0, jj);
      float w1 = __shfl(e1, jj);
      float w2 = __shfl(e2, jj);
      float w3 = __shfl(e3, jj);
      int   sj = __shfl(sv, jj);
      const float2* hr2 = (const float2*)(Hb + (size_t)sj * OUTC);
      float2 h0 = hr2[lane];
      float2 h1 = hr2[64 + lane];
      float2 h2 = hr2[128 + lane];
      float2 h3 = hr2[192 + lane];
      acc[0].x = fmaf(w0, h0.x, acc[0].x); acc[0].y = fmaf(w0, h0.y, acc[0].y);
      acc[1].x = fmaf(w1, h1.x, acc[1].x); acc[1].y = fmaf(w1, h1.y, acc[1].y);
      acc[2].x = fmaf(w2, h2.x, acc[2].x); acc[2].y = fmaf(w2, h2.y, acc[2].y);
      acc[3].x = fmaf(w3, h3.x, acc[3].x); acc[3].y = fmaf(w3, h3.y, acc[3].y);
    }
  }

  float i0 = 1.f / s0, i1 = 1.f / s1, i2 = 1.f / s2, i3 = 1.f / s3;
  float2 b2 = ((const float2*)bias)[lane];
  float x0 = 0.25f * (acc[0].x * i0 + acc[1].x * i1 + acc[2].x * i2 + acc[3].x * i3) + b2.x;
  float x1 = 0.25f * (acc[0].y * i0 + acc[1].y * i1 + acc[2].y * i2 + acc[3].y * i3) + b2.y;

  // LayerNorm over 128 channels (2 per lane) within the wave
  float mu = wsum(x0 + x1) * (1.f / 128.f);
  float d0 = x0 - mu, d1 = x1 - mu;
  float var = wsum(d0 * d0 + d1 * d1) * (1.f / 128.f);
  float inv = rsqrtf(var + LN_EPS);
  float2 g2 = ((const float2*)lng)[lane];
  float2 o2 = ((const float2*)lnb)[lane];
  float2 out;
  out.x = fmaxf(d0 * inv * g2.x + o2.x, 0.f);
  out.y = fmaxf(d1 * inv * g2.y + o2.y, 0.f);
  ((float2*)(Xout + (size_t)n * HIDD))[lane] = out;
}

// ---------------- global mean pool (segmented, batch is sorted) ----------------
__global__ __launch_bounds__(256) void k_pool(const float* __restrict__ X,
                                              const int* __restrict__ bnd,
                                              float* __restrict__ out){
  int g = blockIdx.x;
  int s = bnd[g], e = bnd[g + 1];
  int c = threadIdx.x & 127, part = threadIdx.x >> 7;
  float acc = 0.f;
  for (int n = s + part; n < e; n += 2) acc += X[(size_t)n * HIDD + c];
  __shared__ float red[256];
  red[threadIdx.x] = acc;
  __syncthreads();
  if (part == 0){
    out[g * HIDD + c] = (red[c] + red[128 + c]) / fmaxf((float)(e - s), 1.f);
  }
}

extern "C" void kernel_launch(void* const* d_in, const int* in_sizes, int n_in,
                              void* d_out, int out_size, void* d_ws, size_t ws_size,
                              hipStream_t stream){
  const float* x        = (const float*)d_in[0];
  const float* ea       = (const float*)d_in[1];
  const float* lin_w[3] = {(const float*)d_in[2], (const float*)d_in[3], (const float*)d_in[4]};
  const float* lin_edge = (const float*)d_in[5];
  const float* att_src  = (const float*)d_in[6];
  const float* att_dst  = (const float*)d_in[7];
  const float* att_edge = (const float*)d_in[8];
  const float* bias     = (const float*)d_in[9];
  const float* lng      = (const float*)d_in[10];
  const float* lnb      = (const float*)d_in[11];
  const int*   eidx     = (const int*)d_in[12];
  const int*   batch    = (const int*)d_in[13];
  const int*   srcp = eidx;
  const int*   dstp = eidx + N_EDG;

  char* ws = (char*)d_ws;
  size_t off = 0;
  auto alloc = [&](size_t bytes)->char*{
    size_t o = off;
    off = (off + bytes + 511) & ~(size_t)511;
    return ws + o;
  };
  int*   deg      = (int*)  alloc((size_t)N_NODES * 4);
  int*   rowptr   = (int*)  alloc((size_t)(N_NODES + 1) * 4);
  int*   cursor   = (int*)  alloc((size_t)N_NODES * 4);
  int*   csr_src  = (int*)  alloc((size_t)N_EDG * 4);
  int*   csr_eid  = (int*)  alloc((size_t)N_EDG * 4);
  int*   epos     = (int*)  alloc((size_t)N_EDG * 4);
  int*   bnd      = (int*)  alloc((size_t)(NB + 1) * 4);
  float* lattr    = (float*)alloc((size_t)N_NODES * EMBD * 4);
  float* s_src    = (float*)alloc((size_t)N_NODES * 4 * 4);
  float* s_dst    = (float*)alloc((size_t)N_NODES * 4 * 4);
  float* al_loop  = (float*)alloc((size_t)N_NODES * 4 * 4);
  float* alpc     = (float*)alloc((size_t)N_EDG * 4 * 4);
  float* vfold    = (float*)alloc((size_t)3 * 1152 * 4);
  float* hbuf     = (float*)alloc((size_t)N_NODES * OUTC * 4);
  float* xA       = (float*)alloc((size_t)N_NODES * HIDD * 4);
  float* xB       = (float*)alloc((size_t)N_NODES * HIDD * 4);

  hipMemsetAsync(deg, 0, (size_t)N_NODES * 4, stream);
  k_deg<<<(N_EDG + 255) / 256, 256, 0, stream>>>(dstp, deg);
  k_scan<<<1, 1024, 0, stream>>>(deg, rowptr, cursor);
  k_scatter<<<(N_EDG + 255) / 256, 256, 0, stream>>>(srcp, dstp, cursor, csr_src, csr_eid, epos);
  k_loopattr<<<(N_NODES + 1) / 2, 64, 0, stream>>>(ea, rowptr, csr_eid, lattr);
  k_bounds<<<(N_NODES + 255) / 256, 256, 0, stream>>>(batch, bnd);
  {
    dim3 fg(5, 3);
    k_fold<<<fg, 256, 0, stream>>>(lin_w[0], lin_w[1], lin_w[2], lin_edge,
                                   att_src, att_dst, att_edge, vfold);
  }

  const float* xcur = x;
  float* xout = xA;
  for (int L = 0; L < 3; ++L){
    int in_dim = L ? HIDD : EMBD;
    const float* W  = lin_w[L];
    float* vf = vfold + L * 1152;
    dim3 gg(OUTC / GBN, (N_NODES + GBM - 1) / GBM);
    k_gemm<<<gg, 256, 0, stream>>>(xcur, W, hbuf, N_NODES, in_dim);
    k_nodelin<<<(N_NODES + 255) / 256, 256, 0, stream>>>(xcur, vf, lattr,
        s_src, s_dst, al_loop, in_dim);
    k_edgepart<<<(N_EDG + 255) / 256, 256, 0, stream>>>(ea, srcp, dstp, epos, vf,
        s_src, s_dst, alpc);
    k_aggr<<<(N_NODES + 3) / 4, 256, 0, stream>>>(hbuf, alpc, al_loop, rowptr, csr_src,
        bias + L * HIDD, lng + L * HIDD, lnb + L * HIDD, xout);
    xcur = xout;
    xout = (L == 0) ? xB : xA;
  }

  k_pool<<<NB, 256, 0, stream>>>(xcur, bnd, (float*)d_out);
}

// Round 3
// 486.865 us; speedup vs baseline: 1.6443x; 1.2230x over previous
//
#include <hip/hip_runtime.h>
#include <hip/hip_bf16.h>
#include <math.h>

#define N_NODES 20000
#define N_EDG   320000
#define NB      64
#define EMBD    32
#define HIDD    128
#define NHEAD   4
#define OUTC    512      // H * HID
#define LN_EPS  1e-5f
#define NEG_SLOPE 0.2f

typedef unsigned int u32;

__device__ __forceinline__ float lrelu(float x){ return x >= 0.f ? x : NEG_SLOPE * x; }

// bf16 pair (packed in u32) -> two floats. elem0 = low 16 bits.
__device__ __forceinline__ float2 bf2f(u32 p){
  float2 r;
  r.x = __uint_as_float(p << 16);
  r.y = __uint_as_float(p & 0xffff0000u);
  return r;
}
// two floats -> packed bf16 pair (RNE)
__device__ __forceinline__ u32 pack2bf(float a, float b){
  u32 ua = __float_as_uint(a);
  u32 ub = __float_as_uint(b);
  ua = (ua + 0x7fffu + ((ua >> 16) & 1u)) >> 16;
  ub = (ub + 0x7fffu + ((ub >> 16) & 1u)) >> 16;
  return ua | (ub << 16);
}

// ---------------- CSR construction ----------------
__global__ void k_deg(const int* __restrict__ dst, int* __restrict__ deg){
  int e = blockIdx.x * blockDim.x + threadIdx.x;
  if (e < N_EDG) atomicAdd(&deg[dst[e]], 1);
}

__global__ __launch_bounds__(1024) void k_scan(const int* __restrict__ deg,
                                               int* __restrict__ rowptr,
                                               int* __restrict__ cursor){
  __shared__ int sums[1024];
  const int CH = (N_NODES + 1023) / 1024;   // 20
  int t = threadIdx.x;
  int start = t * CH;
  int end = min(start + CH, N_NODES);
  int s = 0;
  for (int i = start; i < end; ++i) s += deg[i];
  sums[t] = s;
  __syncthreads();
  for (int off = 1; off < 1024; off <<= 1){
    int v = (t >= off) ? sums[t - off] : 0;
    __syncthreads();
    sums[t] += v;
    __syncthreads();
  }
  int run = (t > 0) ? sums[t - 1] : 0;
  for (int i = start; i < end; ++i){
    rowptr[i] = run; cursor[i] = run; run += deg[i];
  }
  if (t == 0) rowptr[N_NODES] = sums[1023];
}

__global__ void k_scatter(const int* __restrict__ src, const int* __restrict__ dst,
                          int* __restrict__ cursor,
                          int* __restrict__ csr_src, int* __restrict__ epos){
  int e = blockIdx.x * blockDim.x + threadIdx.x;
  if (e < N_EDG){
    int d = dst[e];
    int p = atomicAdd(&cursor[d], 1);
    csr_src[p] = src[e];
    epos[e] = p;
  }
}

// loop_attr sums: coalesced read of ea, atomic scatter into [N,32] (L2-resident)
__global__ void k_loopsum(const float* __restrict__ ea, const int* __restrict__ dst,
                          float* __restrict__ lattr){
  int i = blockIdx.x * blockDim.x + threadIdx.x;
  if (i < N_EDG * EMBD){
    int e = i >> 5, k = i & 31;
    atomicAdd(&lattr[(size_t)dst[e] * EMBD + k], ea[i]);
  }
}

// graph boundaries from sorted batch: bnd[g] = first n with batch[n] >= g
__global__ void k_bounds(const int* __restrict__ batch, int* __restrict__ bnd){
  int n = blockIdx.x * blockDim.x + threadIdx.x;
  if (n >= N_NODES) return;
  int b = batch[n];
  int bp = (n == 0) ? -1 : batch[n - 1];
  for (int g = bp + 1; g <= b; ++g) bnd[g] = n;
  if (n == N_NODES - 1){
    for (int g = b + 1; g <= NB; ++g) bnd[g] = N_NODES;
  }
}

// ---------------- attention-vector folding (all 3 layers, one launch) ----------------
// vfold[L] layout: [0,512) v_src[k*4+h], [512,1024) v_dst, [1024,1152) v_e
__global__ void k_fold(const float* __restrict__ W0, const float* __restrict__ W1,
                       const float* __restrict__ W2, const float* __restrict__ lin_edge,
                       const float* __restrict__ att_src, const float* __restrict__ att_dst,
                       const float* __restrict__ att_edge, float* __restrict__ vfold){
  int L = blockIdx.y;
  int in_dim = L ? HIDD : EMBD;
  const float* W  = (L == 0) ? W0 : ((L == 1) ? W1 : W2);
  const float* We = lin_edge + (size_t)L * EMBD * OUTC;
  const float* as = att_src + L * 512;
  const float* ad = att_dst + L * 512;
  const float* ae = att_edge + L * 512;
  float* vf = vfold + L * 1152;
  int j = blockIdx.x * blockDim.x + threadIdx.x;
  int nsrc = in_dim * NHEAD;
  if (j < nsrc){
    int k = j >> 2, h = j & 3;
    float s = 0.f;
    for (int c = 0; c < HIDD; ++c) s += W[k * OUTC + h * HIDD + c] * as[h * HIDD + c];
    vf[k * 4 + h] = s;
  } else if (j < 2 * nsrc){
    int jj = j - nsrc; int k = jj >> 2, h = jj & 3;
    float s = 0.f;
    for (int c = 0; c < HIDD; ++c) s += W[k * OUTC + h * HIDD + c] * ad[h * HIDD + c];
    vf[512 + k * 4 + h] = s;
  } else if (j < 2 * nsrc + EMBD * NHEAD){
    int jj = j - 2 * nsrc; int k = jj >> 2, h = jj & 3;
    float s = 0.f;
    for (int c = 0; c < HIDD; ++c) s += We[k * OUTC + h * HIDD + c] * ae[h * HIDD + c];
    vf[1024 + k * 4 + h] = s;
  }
}

// ---------------- h = X @ W : [M,K]x[K,512] f32 math, bf16 output ----------------
#define GBM 64
#define GBN 128
#define GBK 32
__global__ __launch_bounds__(256) void k_gemm(const float* __restrict__ X,
                                              const float* __restrict__ W,
                                              u32* __restrict__ HbW,   // bf16 pairs, 256 words/row
                                              int M, int K){
  __shared__ float As[GBK][GBM + 4];
  __shared__ float Bs[GBK][GBN + 4];
  int bm = blockIdx.y * GBM, bn = blockIdx.x * GBN;
  int t = threadIdx.x;
  int tx = t & 15, ty = t >> 4;
  float acc[4][8];
  #pragma unroll
  for (int i = 0; i < 4; ++i)
    #pragma unroll
    for (int j = 0; j < 8; ++j) acc[i][j] = 0.f;

  for (int k0 = 0; k0 < K; k0 += GBK){
    #pragma unroll
    for (int i = 0; i < 2; ++i){
      int f = t + i * 256;
      int row = f >> 3, kc = f & 7;
      int gm = bm + row;
      float4 xv = make_float4(0.f, 0.f, 0.f, 0.f);
      if (gm < M) xv = *(const float4*)(X + (size_t)gm * K + k0 + kc * 4);
      As[kc * 4 + 0][row] = xv.x;
      As[kc * 4 + 1][row] = xv.y;
      As[kc * 4 + 2][row] = xv.z;
      As[kc * 4 + 3][row] = xv.w;
    }
    #pragma unroll
    for (int i = 0; i < 4; ++i){
      int f = t + i * 256;
      int kk = f >> 5, nc = f & 31;
      *(float4*)&Bs[kk][nc * 4] = *(const float4*)(W + (size_t)(k0 + kk) * OUTC + bn + nc * 4);
    }
    __syncthreads();
    #pragma unroll
    for (int kk = 0; kk < GBK; ++kk){
      float4 rA  = *(const float4*)&As[kk][ty * 4];
      float4 rB0 = *(const float4*)&Bs[kk][tx * 4];
      float4 rB1 = *(const float4*)&Bs[kk][64 + tx * 4];
      float a[4] = {rA.x, rA.y, rA.z, rA.w};
      float b[8] = {rB0.x, rB0.y, rB0.z, rB0.w, rB1.x, rB1.y, rB1.z, rB1.w};
      #pragma unroll
      for (int i = 0; i < 4; ++i)
        #pragma unroll
        for (int j = 0; j < 8; ++j) acc[i][j] = fmaf(a[i], b[j], acc[i][j]);
    }
    __syncthreads();
  }
  #pragma unroll
  for (int i = 0; i < 4; ++i){
    int gm = bm + ty * 4 + i;
    if (gm < M){
      u32* cr = HbW + (size_t)gm * 256 + (bn >> 1);
      uint2 w0, w1;
      w0.x = pack2bf(acc[i][0], acc[i][1]);
      w0.y = pack2bf(acc[i][2], acc[i][3]);
      w1.x = pack2bf(acc[i][4], acc[i][5]);
      w1.y = pack2bf(acc[i][6], acc[i][7]);
      *(uint2*)(cr + tx * 2)      = w0;
      *(uint2*)(cr + 32 + tx * 2) = w1;
    }
  }
}

// ---------------- per-node logits: s_src, s_dst, self-loop logit ----------------
__global__ __launch_bounds__(256) void k_nodelin(const float* __restrict__ X,
                                                 const float* __restrict__ vfold,
                                                 const float* __restrict__ lattr,
                                                 const int* __restrict__ deg,
                                                 float* __restrict__ s_src, float* __restrict__ s_dst,
                                                 float* __restrict__ al_loop, int in_dim){
  __shared__ float vs[1152];
  for (int i = threadIdx.x; i < 1152; i += 256) vs[i] = vfold[i];
  __syncthreads();
  int n = blockIdx.x * blockDim.x + threadIdx.x;
  if (n >= N_NODES) return;
  float a[4] = {0,0,0,0}, d[4] = {0,0,0,0};
  const float* xr = X + (size_t)n * in_dim;
  for (int k4 = 0; k4 < in_dim; k4 += 4){
    float4 xv = *(const float4*)(xr + k4);
    #pragma unroll
    for (int h = 0; h < 4; ++h){
      a[h] += xv.x * vs[(k4+0)*4+h] + xv.y * vs[(k4+1)*4+h]
            + xv.z * vs[(k4+2)*4+h] + xv.w * vs[(k4+3)*4+h];
      d[h] += xv.x * vs[512+(k4+0)*4+h] + xv.y * vs[512+(k4+1)*4+h]
            + xv.z * vs[512+(k4+2)*4+h] + xv.w * vs[512+(k4+3)*4+h];
    }
  }
  float ev[4] = {0,0,0,0};
  const float* lr = lattr + (size_t)n * EMBD;
  #pragma unroll
  for (int k4 = 0; k4 < EMBD; k4 += 4){
    float4 lv = *(const float4*)(lr + k4);
    #pragma unroll
    for (int h = 0; h < 4; ++h){
      ev[h] += lv.x * vs[1024+(k4+0)*4+h] + lv.y * vs[1024+(k4+1)*4+h]
             + lv.z * vs[1024+(k4+2)*4+h] + lv.w * vs[1024+(k4+3)*4+h];
    }
  }
  float invd = 1.f / fmaxf((float)deg[n], 1.f);
  ((float4*)s_src)[n] = make_float4(a[0], a[1], a[2], a[3]);
  ((float4*)s_dst)[n] = make_float4(d[0], d[1], d[2], d[3]);
  float4 ll;
  ll.x = lrelu(a[0]+d[0]+ev[0]*invd); ll.y = lrelu(a[1]+d[1]+ev[1]*invd);
  ll.z = lrelu(a[2]+d[2]+ev[2]*invd); ll.w = lrelu(a[3]+d[3]+ev[3]*invd);
  ((float4*)al_loop)[n] = ll;
}

// ---------------- per-edge FULL logit (leaky applied), written in CSR order ----------------
__global__ __launch_bounds__(256) void k_edgepart(const float* __restrict__ ea,
                                                  const int* __restrict__ src,
                                                  const int* __restrict__ dst,
                                                  const int* __restrict__ epos,
                                                  const float* __restrict__ vfold,
                                                  const float* __restrict__ s_src,
                                                  const float* __restrict__ s_dst,
                                                  float* __restrict__ alpc){
  __shared__ float ve[128];
  if (threadIdx.x < 128) ve[threadIdx.x] = vfold[1024 + threadIdx.x];
  __syncthreads();
  int e = blockIdx.x * blockDim.x + threadIdx.x;
  if (e >= N_EDG) return;
  float ev[4] = {0,0,0,0};
  const float* er = ea + (size_t)e * EMBD;
  #pragma unroll
  for (int k4 = 0; k4 < EMBD; k4 += 4){
    float4 v = *(const float4*)(er + k4);
    #pragma unroll
    for (int h = 0; h < 4; ++h){
      ev[h] += v.x * ve[(k4+0)*4+h] + v.y * ve[(k4+1)*4+h]
             + v.z * ve[(k4+2)*4+h] + v.w * ve[(k4+3)*4+h];
    }
  }
  float4 ss = ((const float4*)s_src)[src[e]];
  float4 dd = ((const float4*)s_dst)[dst[e]];
  float4 o;
  o.x = lrelu(ss.x + dd.x + ev[0]);
  o.y = lrelu(ss.y + dd.y + ev[1]);
  o.z = lrelu(ss.z + dd.z + ev[2]);
  o.w = lrelu(ss.w + dd.w + ev[3]);
  ((float4*)alpc)[epos[e]] = o;
}

// ---------------- wave-per-node aggregation + head mean + bias + LN + ReLU ----------------
__device__ __forceinline__ float wmax(float v){
  #pragma unroll
  for (int off = 32; off > 0; off >>= 1) v = fmaxf(v, __shfl_xor(v, off));
  return v;
}
__device__ __forceinline__ float wsum(float v){
  #pragma unroll
  for (int off = 32; off > 0; off >>= 1) v += __shfl_xor(v, off);
  return v;
}

__global__ __launch_bounds__(256) void k_aggr(const u32* __restrict__ HbW,
                                              const float* __restrict__ alpc,
                                              const float* __restrict__ al_loop,
                                              const int* __restrict__ rowptr,
                                              const int* __restrict__ csr_src,
                                              const float* __restrict__ bias,
                                              const float* __restrict__ lng,
                                              const float* __restrict__ lnb,
                                              float* __restrict__ Xout){
  int wid  = threadIdx.x >> 6;
  int lane = threadIdx.x & 63;
  int n = blockIdx.x * 4 + wid;
  if (n >= N_NODES) return;
  int rs = rowptr[n], re = rowptr[n + 1];

  float4 ll = ((const float4*)al_loop)[n];
  float m0 = ll.x, m1 = ll.y, m2 = ll.z, m3 = ll.w;
  float s0 = 1.f, s1 = 1.f, s2 = 1.f, s3 = 1.f;   // self-loop: exp(ll-ll)=1

  // acc[h] covers channels (2*lane, 2*lane+1) of head h; init with self-loop
  const u32* hn = HbW + (size_t)n * 256;
  float2 acc[4];
  #pragma unroll
  for (int h = 0; h < 4; ++h) acc[h] = bf2f(hn[h * 64 + lane]);

  for (int base = rs; base < re; base += 64){
    int cnt = min(64, re - base);
    int j = base + lane;
    float4 v = make_float4(-1e30f, -1e30f, -1e30f, -1e30f);
    int sv = 0;
    if (lane < cnt){
      v = ((const float4*)alpc)[j];
      sv = csr_src[j];
    }
    float nm0 = fmaxf(m0, wmax(v.x));
    float nm1 = fmaxf(m1, wmax(v.y));
    float nm2 = fmaxf(m2, wmax(v.z));
    float nm3 = fmaxf(m3, wmax(v.w));
    float e0 = (lane < cnt) ? __expf(v.x - nm0) : 0.f;
    float e1 = (lane < cnt) ? __expf(v.y - nm1) : 0.f;
    float e2 = (lane < cnt) ? __expf(v.z - nm2) : 0.f;
    float e3 = (lane < cnt) ? __expf(v.w - nm3) : 0.f;
    float r0 = __expf(m0 - nm0), r1 = __expf(m1 - nm1);
    float r2 = __expf(m2 - nm2), r3 = __expf(m3 - nm3);
    s0 = s0 * r0 + wsum(e0);
    s1 = s1 * r1 + wsum(e1);
    s2 = s2 * r2 + wsum(e2);
    s3 = s3 * r3 + wsum(e3);
    acc[0].x *= r0; acc[0].y *= r0;
    acc[1].x *= r1; acc[1].y *= r1;
    acc[2].x *= r2; acc[2].y *= r2;
    acc[3].x *= r3; acc[3].y *= r3;
    m0 = nm0; m1 = nm1; m2 = nm2; m3 = nm3;

    #pragma unroll 4
    for (int jj = 0; jj < cnt; ++jj){
      float w0 = __shfl(e0, jj);
      float w1 = __shfl(e1, jj);
      float w2 = __shfl(e2, jj);
      float w3 = __shfl(e3, jj);
      int   sj = __shfl(sv, jj);
      const u32* hr = HbW + (size_t)sj * 256;
      float2 h0 = bf2f(hr[lane]);
      float2 h1 = bf2f(hr[64 + lane]);
      float2 h2 = bf2f(hr[128 + lane]);
      float2 h3 = bf2f(hr[192 + lane]);
      acc[0].x = fmaf(w0, h0.x, acc[0].x); acc[0].y = fmaf(w0, h0.y, acc[0].y);
      acc[1].x = fmaf(w1, h1.x, acc[1].x); acc[1].y = fmaf(w1, h1.y, acc[1].y);
      acc[2].x = fmaf(w2, h2.x, acc[2].x); acc[2].y = fmaf(w2, h2.y, acc[2].y);
      acc[3].x = fmaf(w3, h3.x, acc[3].x); acc[3].y = fmaf(w3, h3.y, acc[3].y);
    }
  }

  float i0 = 1.f / s0, i1 = 1.f / s1, i2 = 1.f / s2, i3 = 1.f / s3;
  float2 b2 = ((const float2*)bias)[lane];
  float x0 = 0.25f * (acc[0].x * i0 + acc[1].x * i1 + acc[2].x * i2 + acc[3].x * i3) + b2.x;
  float x1 = 0.25f * (acc[0].y * i0 + acc[1].y * i1 + acc[2].y * i2 + acc[3].y * i3) + b2.y;

  // LayerNorm over 128 channels (2 per lane) within the wave
  float mu = wsum(x0 + x1) * (1.f / 128.f);
  float d0 = x0 - mu, d1 = x1 - mu;
  float var = wsum(d0 * d0 + d1 * d1) * (1.f / 128.f);
  float inv = rsqrtf(var + LN_EPS);
  float2 g2 = ((const float2*)lng)[lane];
  float2 o2 = ((const float2*)lnb)[lane];
  float2 out;
  out.x = fmaxf(d0 * inv * g2.x + o2.x, 0.f);
  out.y = fmaxf(d1 * inv * g2.y + o2.y, 0.f);
  ((float2*)(Xout + (size_t)n * HIDD))[lane] = out;
}

// ---------------- global mean pool (segmented, batch is sorted) ----------------
__global__ __launch_bounds__(256) void k_pool(const float* __restrict__ X,
                                              const int* __restrict__ bnd,
                                              float* __restrict__ out){
  int g = blockIdx.x;
  int s = bnd[g], e = bnd[g + 1];
  int c = threadIdx.x & 127, part = threadIdx.x >> 7;
  float acc = 0.f;
  for (int n = s + part; n < e; n += 2) acc += X[(size_t)n * HIDD + c];
  __shared__ float red[256];
  red[threadIdx.x] = acc;
  __syncthreads();
  if (part == 0){
    out[g * HIDD + c] = (red[c] + red[128 + c]) / fmaxf((float)(e - s), 1.f);
  }
}

extern "C" void kernel_launch(void* const* d_in, const int* in_sizes, int n_in,
                              void* d_out, int out_size, void* d_ws, size_t ws_size,
                              hipStream_t stream){
  const float* x        = (const float*)d_in[0];
  const float* ea       = (const float*)d_in[1];
  const float* lin_w[3] = {(const float*)d_in[2], (const float*)d_in[3], (const float*)d_in[4]};
  const float* lin_edge = (const float*)d_in[5];
  const float* att_src  = (const float*)d_in[6];
  const float* att_dst  = (const float*)d_in[7];
  const float* att_edge = (const float*)d_in[8];
  const float* bias     = (const float*)d_in[9];
  const float* lng      = (const float*)d_in[10];
  const float* lnb      = (const float*)d_in[11];
  const int*   eidx     = (const int*)d_in[12];
  const int*   batch    = (const int*)d_in[13];
  const int*   srcp = eidx;
  const int*   dstp = eidx + N_EDG;

  char* ws = (char*)d_ws;
  size_t off = 0;
  auto alloc = [&](size_t bytes)->char*{
    size_t o = off;
    off = (off + bytes + 511) & ~(size_t)511;
    return ws + o;
  };
  int*   deg      = (int*)  alloc((size_t)N_NODES * 4);
  int*   rowptr   = (int*)  alloc((size_t)(N_NODES + 1) * 4);
  int*   cursor   = (int*)  alloc((size_t)N_NODES * 4);
  int*   csr_src  = (int*)  alloc((size_t)N_EDG * 4);
  int*   epos     = (int*)  alloc((size_t)N_EDG * 4);
  int*   bnd      = (int*)  alloc((size_t)(NB + 1) * 4);
  float* lattr    = (float*)alloc((size_t)N_NODES * EMBD * 4);
  float* s_src    = (float*)alloc((size_t)N_NODES * 4 * 4);
  float* s_dst    = (float*)alloc((size_t)N_NODES * 4 * 4);
  float* al_loop  = (float*)alloc((size_t)N_NODES * 4 * 4);
  float* alpc     = (float*)alloc((size_t)N_EDG * 4 * 4);
  float* vfold    = (float*)alloc((size_t)3 * 1152 * 4);
  u32*   hbufW    = (u32*)  alloc((size_t)N_NODES * 256 * 4);   // bf16 Hb
  float* xA       = (float*)alloc((size_t)N_NODES * HIDD * 4);
  float* xB       = (float*)alloc((size_t)N_NODES * HIDD * 4);

  hipMemsetAsync(deg, 0, (size_t)N_NODES * 4, stream);
  hipMemsetAsync(lattr, 0, (size_t)N_NODES * EMBD * 4, stream);
  k_deg<<<(N_EDG + 255) / 256, 256, 0, stream>>>(dstp, deg);
  k_scan<<<1, 1024, 0, stream>>>(deg, rowptr, cursor);
  k_scatter<<<(N_EDG + 255) / 256, 256, 0, stream>>>(srcp, dstp, cursor, csr_src, epos);
  k_loopsum<<<(N_EDG * EMBD + 255) / 256, 256, 0, stream>>>(ea, dstp, lattr);
  k_bounds<<<(N_NODES + 255) / 256, 256, 0, stream>>>(batch, bnd);
  {
    dim3 fg(5, 3);
    k_fold<<<fg, 256, 0, stream>>>(lin_w[0], lin_w[1], lin_w[2], lin_edge,
                                   att_src, att_dst, att_edge, vfold);
  }

  const float* xcur = x;
  float* xout = xA;
  for (int L = 0; L < 3; ++L){
    int in_dim = L ? HIDD : EMBD;
    const float* W  = lin_w[L];
    float* vf = vfold + L * 1152;
    dim3 gg(OUTC / GBN, (N_NODES + GBM - 1) / GBM);
    k_gemm<<<gg, 256, 0, stream>>>(xcur, W, hbufW, N_NODES, in_dim);
    k_nodelin<<<(N_NODES + 255) / 256, 256, 0, stream>>>(xcur, vf, lattr, deg,
        s_src, s_dst, al_loop, in_dim);
    k_edgepart<<<(N_EDG + 255) / 256, 256, 0, stream>>>(ea, srcp, dstp, epos, vf,
        s_src, s_dst, alpc);
    k_aggr<<<(N_NODES + 3) / 4, 256, 0, stream>>>(hbufW, alpc, al_loop, rowptr, csr_src,
        bias + L * HIDD, lng + L * HIDD, lnb + L * HIDD, xout);
    xcur = xout;
    xout = (L == 0) ? xB : xA;
  }

  k_pool<<<NB, 256, 0, stream>>>(xcur, bnd, (float*)d_out);
}